// Round 8
// baseline (2971.122 us; speedup 1.0000x reference)
//
#include <hip/hip_runtime.h>
#include <hip/hip_bf16.h>
#include <stdint.h>

#define BB 32
#define NN 128
#define TT 16
#define FN 16
#define FE 8
#define FG 8
#define FH 16
#define HH 128
#define DEC 64

// ws layout (floats):
// base_node @0        [524288]
// We        @524288   [1024]
// mg        @525312   [4096]
// m1p       @529408   [524288]
// m2        @1053696  [524288]
// o1        @1577984  [524288]
// hidden    @2102272  [524288]
// eg16      @2626560  [2097152]
// jl (int)  @4723712  [524288]
// cnt (int) @5248000  [4096]
// P         @5252096  [6291456]   (4 ksplit x 3 mats x 4096 rows x 128 cols)
// end 11543552 floats = 46.2 MB (ws is 256 MB)

__global__ __launch_bounds__(HH) void prep1(const float* __restrict__ node,
                                            const float* __restrict__ Wn,
                                            float* __restrict__ base_node,
                                            float* __restrict__ hidden) {
    int row = blockIdx.x;
    int h = threadIdx.x;
    float acc = 0.f;
#pragma unroll
    for (int f = 0; f < FN; ++f)
        acc += node[row * FN + f] * Wn[f * HH + h];
    base_node[row * HH + h] = acc;
    hidden[row * HH + h] = 0.f;
}

// grid = BB + FE blocks: 0..31 compute mg[b][h]; 32..39 compute We[f][h].
__global__ __launch_bounds__(HH) void prep2(const float* __restrict__ graph,
                                            const float* __restrict__ Wg,
                                            const float* __restrict__ Wmg,
                                            const float* __restrict__ Wee,
                                            const float* __restrict__ Wme,
                                            float* __restrict__ mg,
                                            float* __restrict__ We) {
    int h = threadIdx.x;
    if (blockIdx.x < BB) {
        int b = blockIdx.x;
        __shared__ float gf[HH];
        float acc = 0.f;
#pragma unroll
        for (int f = 0; f < FG; ++f) acc += graph[b * FG + f] * Wg[f * HH + h];
        gf[h] = acc;
        __syncthreads();
        float a2 = 0.f;
#pragma unroll 16
        for (int k = 0; k < HH; ++k) a2 += gf[k] * Wmg[k * HH + h];
        mg[b * HH + h] = a2;
    } else {
        int f = blockIdx.x - BB;
        float acc = 0.f;
#pragma unroll 16
        for (int k = 0; k < HH; ++k) acc += Wee[f * HH + k] * Wme[k * HH + h];
        We[f * HH + h] = acc;
    }
}

__device__ __forceinline__ uint32_t bf16rne(float v) {
    uint32_t b = __float_as_uint(v);
    return (b + 0x7fffu + ((b >> 16) & 1u)) >> 16;
}

// Compact valid senders into bf16-packed rows; pad count to multiple of 8
// with duplicates of the first valid entry (max is idempotent).
__global__ __launch_bounds__(HH) void prep3(const float* __restrict__ edge,
                                            const int* __restrict__ adj,
                                            uint4* __restrict__ eg16,
                                            int* __restrict__ jl,
                                            int* __restrict__ cnt) {
    int bi = blockIdx.x;
    int j = threadIdx.x;
    __shared__ int w0cnt, totc, j0s;
    bool valid = adj[(size_t)bi * NN + j] > 0;
    unsigned long long mask = __ballot(valid);
    int lane = j & 63;
    int wave = j >> 6;
    int prefix = __popcll(mask & ((1ull << lane) - 1ull));
    int wcount = __popcll(mask);
    if (wave == 0 && lane == 0) w0cnt = wcount;
    __syncthreads();
    int base = (wave == 1) ? w0cnt : 0;
    if (wave == 1 && lane == 0) totc = w0cnt + wcount;
    int pos = base + prefix;
    if (valid && pos == 0) j0s = j;
    __syncthreads();
    int c = totc;
    int cpad = (c + 7) & ~7;
    if (j == 0) cnt[bi] = cpad;

    if (valid) {
        jl[bi * NN + pos] = j;
        const float* src = edge + ((size_t)bi * NN + j) * FE;
        uint4 r;
        r.x = bf16rne(src[0]) | (bf16rne(src[1]) << 16);
        r.y = bf16rne(src[2]) | (bf16rne(src[3]) << 16);
        r.z = bf16rne(src[4]) | (bf16rne(src[5]) << 16);
        r.w = bf16rne(src[6]) | (bf16rne(src[7]) << 16);
        eg16[(size_t)bi * NN + pos] = r;
    }
    if (c > 0 && j >= c && j < cpad) {
        int j0 = j0s;
        jl[bi * NN + j] = j0;
        const float* src = edge + ((size_t)bi * NN + j0) * FE;
        uint4 r;
        r.x = bf16rne(src[0]) | (bf16rne(src[1]) << 16);
        r.y = bf16rne(src[2]) | (bf16rne(src[3]) << 16);
        r.z = bf16rne(src[4]) | (bf16rne(src[5]) << 16);
        r.w = bf16rne(src[6]) | (bf16rne(src[7]) << 16);
        eg16[(size_t)bi * NN + j] = r;
    }
}

// K1: 1024 blocks = 256 row-tiles x 4 k-quarters; 256 threads (4 waves).
// Block computes 16 rows x 384 cols (all 3 mats) over 64 k, writing partials.
// Thread = 2 rows x 12 cols (4 per mat). Per k: 1 LDS b64 + 3 weight b128 + 24 FMA.
__global__ __launch_bounds__(256) void k1_gemm(
    const float* __restrict__ base_node, const float* __restrict__ hidden,
    const float* __restrict__ hints, const float* __restrict__ Wh,
    const float* __restrict__ Wm1, const float* __restrict__ Wm2,
    const float* __restrict__ Wo1, float* __restrict__ P, int t) {
    __shared__ float zT[64][18];        // [k_local][row], pitch 18
    const int tid = threadIdx.x;
    const int bid = blockIdx.x;
    const int xcd = bid & 7;
    const int rest = bid >> 3;          // 0..127
    const int tile = xcd * 32 + (rest & 31);   // 0..255
    const int qs = rest >> 5;           // k-quarter 0..3
    const int row0 = tile * 16;
    const int ks = qs * 64;

    // ---- stage zT[kl][row]: thread = (kl = tid&63, row-quad rq = tid>>6) ----
    {
        const int kl = tid & 63;
        const int rq = tid >> 6;        // wave id: 0..3 (wave-uniform)
        const int k = ks + kl;
        if (qs < 2) {                   // node_fts part (k < 128)
            float wh[FH];
            if (t > 0) {
#pragma unroll
                for (int f = 0; f < FH; ++f) wh[f] = Wh[f * HH + k];
            }
#pragma unroll
            for (int r = 0; r < 4; ++r) {
                int row = row0 + rq * 4 + r;
                float nf = base_node[row * HH + k];
                if (t > 0) {
                    const float* hr = hints + ((size_t)(t - 1) * BB * NN + row) * FH;
#pragma unroll
                    for (int f = 0; f < FH; ++f) nf = fmaf(hr[f], wh[f], nf);
                }
                zT[kl][rq * 4 + r] = nf;
            }
        } else {                        // hidden part (k >= 128)
#pragma unroll
            for (int r = 0; r < 4; ++r) {
                int row = row0 + rq * 4 + r;
                zT[kl][rq * 4 + r] = hidden[row * HH + (k - HH)];
            }
        }
    }
    __syncthreads();

    const int rowg = tid >> 5;          // 0..7 -> rows rowg*2, rowg*2+1
    const int c0 = (tid & 31) * 4;      // col group of 4 (per mat)

    float acc[2][12];
#pragma unroll
    for (int r = 0; r < 2; ++r)
#pragma unroll
        for (int c = 0; c < 12; ++c) acc[r][c] = 0.f;

    float2 zb[4];
    float4 w1b[4], w2b[4], w3b[4];

#define LOADK(S, KL)                                                       \
    {                                                                      \
        zb[S] = *(const float2*)&zT[KL][rowg * 2];                         \
        const int kg = ks + (KL);                                          \
        w1b[S] = *(const float4*)&Wm1[kg * HH + c0];                       \
        w2b[S] = *(const float4*)&Wm2[kg * HH + c0];                       \
        w3b[S] = *(const float4*)&Wo1[kg * HH + c0];                       \
    }
#define COMPK(S)                                                           \
    {                                                                      \
        const float z0 = zb[S].x, z1 = zb[S].y;                            \
        float wv[12] = {w1b[S].x, w1b[S].y, w1b[S].z, w1b[S].w,            \
                        w2b[S].x, w2b[S].y, w2b[S].z, w2b[S].w,            \
                        w3b[S].x, w3b[S].y, w3b[S].z, w3b[S].w};           \
        _Pragma("unroll") for (int c = 0; c < 12; ++c) {                   \
            acc[0][c] = fmaf(z0, wv[c], acc[0][c]);                        \
            acc[1][c] = fmaf(z1, wv[c], acc[1][c]);                        \
        }                                                                  \
    }

    LOADK(0, 0) LOADK(1, 1) LOADK(2, 2)
    for (int k4 = 0; k4 < 16; ++k4) {
        const int k = k4 * 4;
        const int p1 = (k + 4 < 64) ? k + 4 : 0;
        const int p2 = (k + 5 < 64) ? k + 5 : 0;
        const int p3 = (k + 6 < 64) ? k + 6 : 0;
        LOADK(3, k + 3) COMPK(0)
        LOADK(0, p1)    COMPK(1)
        LOADK(1, p2)    COMPK(2)
        LOADK(2, p3)    COMPK(3)
    }
#undef LOADK
#undef COMPK

    // write partials: P[qs][m][row][col]
#pragma unroll
    for (int r = 0; r < 2; ++r) {
        const int row = row0 + rowg * 2 + r;
#pragma unroll
        for (int m = 0; m < 3; ++m) {
            float4 v = make_float4(acc[r][m * 4 + 0], acc[r][m * 4 + 1],
                                   acc[r][m * 4 + 2], acc[r][m * 4 + 3]);
            *(float4*)&P[(((size_t)(qs * 3 + m) * 4096) + row) * HH + c0] = v;
        }
    }
}

// Reduce the 4 k-split partials into m1p (+mg), m2, o1.
__global__ __launch_bounds__(256) void k1_reduce(
    const float* __restrict__ P, const float* __restrict__ mg,
    float* __restrict__ m1p, float* __restrict__ m2, float* __restrict__ o1) {
    const int bid = blockIdx.x;         // 1536
    const int xcd = bid & 7;
    const int lid = bid >> 3;           // 0..191
    const int idx = lid * 256 + threadIdx.x;   // 0..49151
    const int row_local = idx / 96;     // 0..511
    const int c4 = idx - row_local * 96;
    const int col = c4 * 4;             // 0..380
    const int m = col >> 7;             // 0..2
    const int colm = col & 127;
    const int row = xcd * 512 + row_local;

    const size_t sstride = (size_t)3 * 4096 * HH;
    const size_t base = ((size_t)m * 4096 + row) * HH + colm;
    float4 a0 = *(const float4*)&P[base];
    float4 a1 = *(const float4*)&P[base + sstride];
    float4 a2 = *(const float4*)&P[base + 2 * sstride];
    float4 a3 = *(const float4*)&P[base + 3 * sstride];
    float4 s = make_float4(a0.x + a1.x + a2.x + a3.x,
                           a0.y + a1.y + a2.y + a3.y,
                           a0.z + a1.z + a2.z + a3.z,
                           a0.w + a1.w + a2.w + a3.w);
    const size_t o = (size_t)row * HH + colm;
    if (m == 0) {
        float4 g = *(const float4*)&mg[(row >> 7) * HH + colm];
        s.x += g.x; s.y += g.y; s.z += g.z; s.w += g.w;
        *(float4*)&m1p[o] = s;
    } else if (m == 1) {
        *(float4*)&m2[o] = s;
    } else {
        *(float4*)&o1[o] = s;
    }
}

// K2: 128 threads (h), serial compacted j-loop, unroll-8 batches, bf16 eg rows.
__global__ __launch_bounds__(HH) void k2_max(
    const uint4* __restrict__ eg16, const int* __restrict__ jl,
    const int* __restrict__ cnt, const float* __restrict__ We,
    const float* __restrict__ m1p, const float* __restrict__ m2,
    const float* __restrict__ o1, const float* __restrict__ Wo2,
    const float* __restrict__ Wdn, const float* __restrict__ Wde,
    float* __restrict__ hidden, float* __restrict__ out, int t, int last) {
    __shared__ float agg_lds[HH];
    __shared__ float hnew_lds[HH];
    const int h = threadIdx.x;
    const int bid = blockIdx.x;
    const int bi = (bid & 7) * 512 + (bid >> 3);
    const int b = bi >> 7;

    const float we0 = We[0 * HH + h], we1 = We[1 * HH + h];
    const float we2 = We[2 * HH + h], we3 = We[3 * HH + h];
    const float we4 = We[4 * HH + h], we5 = We[5 * HH + h];
    const float we6 = We[6 * HH + h], we7 = We[7 * HH + h];

    const uint4* __restrict__ egp = eg16 + (size_t)bi * NN;
    const int* __restrict__ jlb = jl + bi * NN;
    const float* __restrict__ m2b = m2 + (size_t)b * NN * HH;
    const int cp = cnt[bi];
    const float m1v = m1p[bi * HH + h];
    const float o1v = o1[bi * HH + h];

    float M = -3e38f;
    const int nch = cp >> 3;
    for (int ch = 0; ch < nch; ++ch) {
        const int k0 = ch * 8;
        uint4 raw[8];
        int jj[8];
        float mv[8];
#pragma unroll
        for (int s = 0; s < 8; ++s) raw[s] = egp[k0 + s];
#pragma unroll
        for (int s = 0; s < 8; ++s) jj[s] = jlb[k0 + s];
#pragma unroll
        for (int s = 0; s < 8; ++s) mv[s] = m2b[jj[s] * HH + h];
#pragma unroll
        for (int s = 0; s < 8; ++s) {
            uint32_t x = raw[s].x, y = raw[s].y, z = raw[s].z, w = raw[s].w;
            float e = __uint_as_float(x << 16) * we0;
            e = fmaf(__uint_as_float(x & 0xffff0000u), we1, e);
            e = fmaf(__uint_as_float(y << 16), we2, e);
            e = fmaf(__uint_as_float(y & 0xffff0000u), we3, e);
            e = fmaf(__uint_as_float(z << 16), we4, e);
            e = fmaf(__uint_as_float(z & 0xffff0000u), we5, e);
            e = fmaf(__uint_as_float(w << 16), we6, e);
            e = fmaf(__uint_as_float(w & 0xffff0000u), we7, e);
            M = fmaxf(M, e + mv[s]);
        }
    }
    float agg = (cp > 0) ? fmaxf(m1v + M, 0.f) : -1e9f;
    agg_lds[h] = agg;
    __syncthreads();

    float acc = o1v;
    const float4* a4 = (const float4*)agg_lds;
#pragma unroll 8
    for (int kk = 0; kk < 32; ++kk) {
        float4 a = a4[kk];
        acc = fmaf(a.x, Wo2[(kk * 4 + 0) * HH + h], acc);
        acc = fmaf(a.y, Wo2[(kk * 4 + 1) * HH + h], acc);
        acc = fmaf(a.z, Wo2[(kk * 4 + 2) * HH + h], acc);
        acc = fmaf(a.w, Wo2[(kk * 4 + 3) * HH + h], acc);
    }
    float hv = fmaxf(acc, 0.f);
    hidden[bi * HH + h] = hv;

    if (last) {
        hnew_lds[h] = hv;
        __syncthreads();
        if (h < DEC) {
            float a = 0.f, e2 = 0.f;
            const float4* h4p = (const float4*)hnew_lds;
#pragma unroll 8
            for (int kk = 0; kk < 32; ++kk) {
                float4 hv4 = h4p[kk];
                float4 av4 = a4[kk];
                a = fmaf(hv4.x, Wdn[(kk * 4 + 0) * DEC + h], a);
                a = fmaf(hv4.y, Wdn[(kk * 4 + 1) * DEC + h], a);
                a = fmaf(hv4.z, Wdn[(kk * 4 + 2) * DEC + h], a);
                a = fmaf(hv4.w, Wdn[(kk * 4 + 3) * DEC + h], a);
                e2 = fmaf(av4.x, Wde[(kk * 4 + 0) * DEC + h], e2);
                e2 = fmaf(av4.y, Wde[(kk * 4 + 1) * DEC + h], e2);
                e2 = fmaf(av4.z, Wde[(kk * 4 + 2) * DEC + h], e2);
                e2 = fmaf(av4.w, Wde[(kk * 4 + 3) * DEC + h], e2);
            }
            out[(((size_t)t * BB + b) * NN + (bi & 127)) * DEC + h] = a + e2;
        }
    }
}

extern "C" void kernel_launch(void* const* d_in, const int* in_sizes, int n_in,
                              void* d_out, int out_size, void* d_ws, size_t ws_size,
                              hipStream_t stream) {
    const float* node = (const float*)d_in[0];
    const float* edge = (const float*)d_in[1];
    const float* graph = (const float*)d_in[2];
    const float* hints = (const float*)d_in[3];
    const int* adj = (const int*)d_in[4];
    const float* Wn = (const float*)d_in[5];
    const float* Wh = (const float*)d_in[6];
    const float* Wee = (const float*)d_in[7];
    const float* Wg = (const float*)d_in[8];
    const float* Wm1 = (const float*)d_in[9];
    const float* Wm2 = (const float*)d_in[10];
    const float* Wme = (const float*)d_in[11];
    const float* Wmg = (const float*)d_in[12];
    const float* Wo1 = (const float*)d_in[13];
    const float* Wo2 = (const float*)d_in[14];
    const float* Wdn = (const float*)d_in[15];
    const float* Wde = (const float*)d_in[16];

    float* ws = (float*)d_ws;
    float* base_node = ws;
    float* We = ws + 524288;
    float* mg = ws + 525312;
    float* m1p = ws + 529408;
    float* m2 = ws + 1053696;
    float* o1 = ws + 1577984;
    float* hidden = ws + 2102272;
    uint4* eg16 = (uint4*)(ws + 2626560);
    int* jl = (int*)(ws + 4723712);
    int* cnt = (int*)(ws + 5248000);
    float* P = ws + 5252096;
    float* out = (float*)d_out;

    prep1<<<BB * NN, HH, 0, stream>>>(node, Wn, base_node, hidden);
    prep2<<<BB + FE, HH, 0, stream>>>(graph, Wg, Wmg, Wee, Wme, mg, We);
    prep3<<<BB * NN, HH, 0, stream>>>(edge, adj, eg16, jl, cnt);

    for (int t = 0; t < TT; ++t) {
        for (int ms = 0; ms < 3; ++ms) {
            k1_gemm<<<1024, 256, 0, stream>>>(base_node, hidden, hints, Wh,
                                              Wm1, Wm2, Wo1, P, t);
            k1_reduce<<<1536, 256, 0, stream>>>(P, mg, m1p, m2, o1);
            k2_max<<<BB * NN, HH, 0, stream>>>(eg16, jl, cnt, We, m1p, m2, o1,
                                               Wo2, Wdn, Wde, hidden, out, t,
                                               ms == 2 ? 1 : 0);
        }
    }
}

// Round 9
// 2240.820 us; speedup vs baseline: 1.3259x; 1.3259x over previous
//
#include <hip/hip_runtime.h>
#include <hip/hip_bf16.h>
#include <stdint.h>

#define BB 32
#define NN 128
#define TT 16
#define FN 16
#define FE 8
#define FG 8
#define FH 16
#define HH 128
#define DEC 64

// ws layout (floats):
// base_node @0        [524288]
// We        @524288   [1024]
// mg        @525312   [4096]
// m1p       @529408   [524288]
// m2        @1053696  [524288]
// o1        @1577984  [524288]
// z         @2102272  [1048576]  ([4096][256] = nf | hidden)
// eg16      @3150848  [2097152]  (bf16-packed compacted edge rows)
// jl (int)  @5248000  [524288]
// cnt (int) @5772288  [4096]
// end 5776384 floats = 23.1 MB

__global__ __launch_bounds__(HH) void prep1(const float* __restrict__ node,
                                            const float* __restrict__ Wn,
                                            float* __restrict__ base_node,
                                            float* __restrict__ zg) {
    int row = blockIdx.x;
    int h = threadIdx.x;
    float acc = 0.f;
#pragma unroll
    for (int f = 0; f < FN; ++f)
        acc += node[row * FN + f] * Wn[f * HH + h];
    base_node[row * HH + h] = acc;
    zg[(size_t)row * 256 + h] = acc;          // nf for t=0 (no hint)
    zg[(size_t)row * 256 + 128 + h] = 0.f;    // hidden = 0
}

// grid = BB + FE blocks: 0..31 compute mg[b][h]; 32..39 compute We[f][h].
__global__ __launch_bounds__(HH) void prep2(const float* __restrict__ graph,
                                            const float* __restrict__ Wg,
                                            const float* __restrict__ Wmg,
                                            const float* __restrict__ Wee,
                                            const float* __restrict__ Wme,
                                            float* __restrict__ mg,
                                            float* __restrict__ We) {
    int h = threadIdx.x;
    if (blockIdx.x < BB) {
        int b = blockIdx.x;
        __shared__ float gf[HH];
        float acc = 0.f;
#pragma unroll
        for (int f = 0; f < FG; ++f) acc += graph[b * FG + f] * Wg[f * HH + h];
        gf[h] = acc;
        __syncthreads();
        float a2 = 0.f;
#pragma unroll 16
        for (int k = 0; k < HH; ++k) a2 += gf[k] * Wmg[k * HH + h];
        mg[b * HH + h] = a2;
    } else {
        int f = blockIdx.x - BB;
        float acc = 0.f;
#pragma unroll 16
        for (int k = 0; k < HH; ++k) acc += Wee[f * HH + k] * Wme[k * HH + h];
        We[f * HH + h] = acc;
    }
}

__device__ __forceinline__ uint32_t bf16rne(float v) {
    uint32_t b = __float_as_uint(v);
    return (b + 0x7fffu + ((b >> 16) & 1u)) >> 16;
}

// Compact valid senders into bf16-packed rows; pad count to multiple of 8
// with duplicates of the first valid entry (max is idempotent).
__global__ __launch_bounds__(HH) void prep3(const float* __restrict__ edge,
                                            const int* __restrict__ adj,
                                            uint4* __restrict__ eg16,
                                            int* __restrict__ jl,
                                            int* __restrict__ cnt) {
    int bi = blockIdx.x;
    int j = threadIdx.x;
    __shared__ int w0cnt, totc, j0s;
    bool valid = adj[(size_t)bi * NN + j] > 0;
    unsigned long long mask = __ballot(valid);
    int lane = j & 63;
    int wave = j >> 6;
    int prefix = __popcll(mask & ((1ull << lane) - 1ull));
    int wcount = __popcll(mask);
    if (wave == 0 && lane == 0) w0cnt = wcount;
    __syncthreads();
    int base = (wave == 1) ? w0cnt : 0;
    if (wave == 1 && lane == 0) totc = w0cnt + wcount;
    int pos = base + prefix;
    if (valid && pos == 0) j0s = j;
    __syncthreads();
    int c = totc;
    int cpad = (c + 7) & ~7;
    if (j == 0) cnt[bi] = cpad;

    if (valid) {
        jl[bi * NN + pos] = j;
        const float* src = edge + ((size_t)bi * NN + j) * FE;
        uint4 r;
        r.x = bf16rne(src[0]) | (bf16rne(src[1]) << 16);
        r.y = bf16rne(src[2]) | (bf16rne(src[3]) << 16);
        r.z = bf16rne(src[4]) | (bf16rne(src[5]) << 16);
        r.w = bf16rne(src[6]) | (bf16rne(src[7]) << 16);
        eg16[(size_t)bi * NN + pos] = r;
    }
    if (c > 0 && j >= c && j < cpad) {
        int j0 = j0s;
        jl[bi * NN + j] = j0;
        const float* src = edge + ((size_t)bi * NN + j0) * FE;
        uint4 r;
        r.x = bf16rne(src[0]) | (bf16rne(src[1]) << 16);
        r.y = bf16rne(src[2]) | (bf16rne(src[3]) << 16);
        r.z = bf16rne(src[4]) | (bf16rne(src[5]) << 16);
        r.w = bf16rne(src[6]) | (bf16rne(src[7]) << 16);
        eg16[(size_t)bi * NN + j] = r;
    }
}

// K1: 512 blocks x 256 threads. Block = 8 rows x 384 cols.
// Wave-uniform rows: waves 0,1 -> rows 0-3; waves 2,3 -> rows 4-7 (readfirstlane).
// z read from GLOBAL via uniform (scalar) loads -> zero LDS traffic.
// Weights read coalesced [k][h] b32. Thread = 4 rows x 3 mats, k-ascending FMA.
__global__ __launch_bounds__(256) void k1_gemm(
    const float* __restrict__ zg,
    const float* __restrict__ Wm1, const float* __restrict__ Wm2,
    const float* __restrict__ Wo1, const float* __restrict__ mg,
    float* __restrict__ m1p, float* __restrict__ m2, float* __restrict__ o1) {
    const int lane = threadIdx.x & 127;
    const int half_u = __builtin_amdgcn_readfirstlane(threadIdx.x >> 7);
    const int bid = blockIdx.x;
    const int tile = (bid & 7) * 64 + (bid >> 3);   // XCD-swizzled, 512 tiles
    const int row0 = tile * 8 + half_u * 4;

    const float* __restrict__ zr0 = zg + (size_t)row0 * 256;
    const float* __restrict__ zr1 = zr0 + 256;
    const float* __restrict__ zr2 = zr0 + 512;
    const float* __restrict__ zr3 = zr0 + 768;

    float acc[4][3];
#pragma unroll
    for (int r = 0; r < 4; ++r) {
        acc[r][0] = 0.f; acc[r][1] = 0.f; acc[r][2] = 0.f;
    }

#pragma unroll 2
    for (int kk = 0; kk < 64; ++kk) {
        const int k0 = kk * 4;
        float4 za = *(const float4*)(zr0 + k0);   // uniform address -> scalar load
        float4 zb = *(const float4*)(zr1 + k0);
        float4 zc = *(const float4*)(zr2 + k0);
        float4 zd = *(const float4*)(zr3 + k0);
#define K1U(COMP, KO)                                                   \
        {                                                               \
            const float w1 = Wm1[(k0 + KO) * HH + lane];                \
            const float w2 = Wm2[(k0 + KO) * HH + lane];                \
            const float w3 = Wo1[(k0 + KO) * HH + lane];                \
            acc[0][0] = fmaf(za.COMP, w1, acc[0][0]);                   \
            acc[1][0] = fmaf(zb.COMP, w1, acc[1][0]);                   \
            acc[2][0] = fmaf(zc.COMP, w1, acc[2][0]);                   \
            acc[3][0] = fmaf(zd.COMP, w1, acc[3][0]);                   \
            acc[0][1] = fmaf(za.COMP, w2, acc[0][1]);                   \
            acc[1][1] = fmaf(zb.COMP, w2, acc[1][1]);                   \
            acc[2][1] = fmaf(zc.COMP, w2, acc[2][1]);                   \
            acc[3][1] = fmaf(zd.COMP, w2, acc[3][1]);                   \
            acc[0][2] = fmaf(za.COMP, w3, acc[0][2]);                   \
            acc[1][2] = fmaf(zb.COMP, w3, acc[1][2]);                   \
            acc[2][2] = fmaf(zc.COMP, w3, acc[2][2]);                   \
            acc[3][2] = fmaf(zd.COMP, w3, acc[3][2]);                   \
        }
        K1U(x, 0) K1U(y, 1) K1U(z, 2) K1U(w, 3)
#undef K1U
    }

    const int b = row0 >> 7;
    const float mgv = mg[b * HH + lane];
#pragma unroll
    for (int r = 0; r < 4; ++r) {
        const int row = row0 + r;
        m1p[row * HH + lane] = acc[r][0] + mgv;
        m2[row * HH + lane] = acc[r][1];
        o1[row * HH + lane] = acc[r][2];
    }
}

// K2: 128 threads (h), serial compacted j-loop, unroll-8 batches, bf16 eg rows.
// Writes hidden into z[:,128:]; on last round also writes nf(t+1) into z[:,:128]
// (folds the hint encoder) and the decoder output.
__global__ __launch_bounds__(HH) void k2_max(
    const uint4* __restrict__ eg16, const int* __restrict__ jl,
    const int* __restrict__ cnt, const float* __restrict__ We,
    const float* __restrict__ m1p, const float* __restrict__ m2,
    const float* __restrict__ o1, const float* __restrict__ Wo2,
    const float* __restrict__ Wdn, const float* __restrict__ Wde,
    const float* __restrict__ base_node, const float* __restrict__ hints,
    const float* __restrict__ Wh, float* __restrict__ zg,
    float* __restrict__ out, int t, int last) {
    __shared__ float agg_lds[HH];
    __shared__ float hnew_lds[HH];
    const int h = threadIdx.x;
    const int bid = blockIdx.x;
    const int bi = (bid & 7) * 512 + (bid >> 3);
    const int b = bi >> 7;

    const float we0 = We[0 * HH + h], we1 = We[1 * HH + h];
    const float we2 = We[2 * HH + h], we3 = We[3 * HH + h];
    const float we4 = We[4 * HH + h], we5 = We[5 * HH + h];
    const float we6 = We[6 * HH + h], we7 = We[7 * HH + h];

    const uint4* __restrict__ egp = eg16 + (size_t)bi * NN;
    const int* __restrict__ jlb = jl + bi * NN;
    const float* __restrict__ m2b = m2 + (size_t)b * NN * HH;
    const int cp = cnt[bi];
    const float m1v = m1p[bi * HH + h];
    const float o1v = o1[bi * HH + h];

    float M = -3e38f;
    const int nch = cp >> 3;
    for (int ch = 0; ch < nch; ++ch) {
        const int k0 = ch * 8;
        uint4 raw[8];
        int jj[8];
        float mv[8];
#pragma unroll
        for (int s = 0; s < 8; ++s) raw[s] = egp[k0 + s];
#pragma unroll
        for (int s = 0; s < 8; ++s) jj[s] = jlb[k0 + s];
#pragma unroll
        for (int s = 0; s < 8; ++s) mv[s] = m2b[jj[s] * HH + h];
#pragma unroll
        for (int s = 0; s < 8; ++s) {
            uint32_t x = raw[s].x, y = raw[s].y, z = raw[s].z, w = raw[s].w;
            float e = __uint_as_float(x << 16) * we0;
            e = fmaf(__uint_as_float(x & 0xffff0000u), we1, e);
            e = fmaf(__uint_as_float(y << 16), we2, e);
            e = fmaf(__uint_as_float(y & 0xffff0000u), we3, e);
            e = fmaf(__uint_as_float(z << 16), we4, e);
            e = fmaf(__uint_as_float(z & 0xffff0000u), we5, e);
            e = fmaf(__uint_as_float(w << 16), we6, e);
            e = fmaf(__uint_as_float(w & 0xffff0000u), we7, e);
            M = fmaxf(M, e + mv[s]);
        }
    }
    float agg = (cp > 0) ? fmaxf(m1v + M, 0.f) : -1e9f;
    agg_lds[h] = agg;
    __syncthreads();

    float acc = o1v;
    const float4* a4 = (const float4*)agg_lds;
#pragma unroll 8
    for (int kk = 0; kk < 32; ++kk) {
        float4 a = a4[kk];
        acc = fmaf(a.x, Wo2[(kk * 4 + 0) * HH + h], acc);
        acc = fmaf(a.y, Wo2[(kk * 4 + 1) * HH + h], acc);
        acc = fmaf(a.z, Wo2[(kk * 4 + 2) * HH + h], acc);
        acc = fmaf(a.w, Wo2[(kk * 4 + 3) * HH + h], acc);
    }
    float hv = fmaxf(acc, 0.f);
    zg[(size_t)bi * 256 + 128 + h] = hv;   // hidden for next k1

    if (last) {
        // nf for step t+1 (hint index = t)
        if (t < TT - 1) {
            const float* __restrict__ hr = hints + ((size_t)t * BB * NN + bi) * FH;
            float nf = base_node[bi * HH + h];
#pragma unroll
            for (int f = 0; f < FH; ++f) nf = fmaf(hr[f], Wh[f * HH + h], nf);
            zg[(size_t)bi * 256 + h] = nf;
        }
        hnew_lds[h] = hv;
        __syncthreads();
        if (h < DEC) {
            float a = 0.f, e2 = 0.f;
            const float4* h4p = (const float4*)hnew_lds;
#pragma unroll 8
            for (int kk = 0; kk < 32; ++kk) {
                float4 hv4 = h4p[kk];
                float4 av4 = a4[kk];
                a = fmaf(hv4.x, Wdn[(kk * 4 + 0) * DEC + h], a);
                a = fmaf(hv4.y, Wdn[(kk * 4 + 1) * DEC + h], a);
                a = fmaf(hv4.z, Wdn[(kk * 4 + 2) * DEC + h], a);
                a = fmaf(hv4.w, Wdn[(kk * 4 + 3) * DEC + h], a);
                e2 = fmaf(av4.x, Wde[(kk * 4 + 0) * DEC + h], e2);
                e2 = fmaf(av4.y, Wde[(kk * 4 + 1) * DEC + h], e2);
                e2 = fmaf(av4.z, Wde[(kk * 4 + 2) * DEC + h], e2);
                e2 = fmaf(av4.w, Wde[(kk * 4 + 3) * DEC + h], e2);
            }
            out[(((size_t)t * BB + b) * NN + (bi & 127)) * DEC + h] = a + e2;
        }
    }
}

extern "C" void kernel_launch(void* const* d_in, const int* in_sizes, int n_in,
                              void* d_out, int out_size, void* d_ws, size_t ws_size,
                              hipStream_t stream) {
    const float* node = (const float*)d_in[0];
    const float* edge = (const float*)d_in[1];
    const float* graph = (const float*)d_in[2];
    const float* hints = (const float*)d_in[3];
    const int* adj = (const int*)d_in[4];
    const float* Wn = (const float*)d_in[5];
    const float* Wh = (const float*)d_in[6];
    const float* Wee = (const float*)d_in[7];
    const float* Wg = (const float*)d_in[8];
    const float* Wm1 = (const float*)d_in[9];
    const float* Wm2 = (const float*)d_in[10];
    const float* Wme = (const float*)d_in[11];
    const float* Wmg = (const float*)d_in[12];
    const float* Wo1 = (const float*)d_in[13];
    const float* Wo2 = (const float*)d_in[14];
    const float* Wdn = (const float*)d_in[15];
    const float* Wde = (const float*)d_in[16];

    float* ws = (float*)d_ws;
    float* base_node = ws;
    float* We = ws + 524288;
    float* mg = ws + 525312;
    float* m1p = ws + 529408;
    float* m2 = ws + 1053696;
    float* o1 = ws + 1577984;
    float* zg = ws + 2102272;
    uint4* eg16 = (uint4*)(ws + 3150848);
    int* jl = (int*)(ws + 5248000);
    int* cnt = (int*)(ws + 5772288);
    float* out = (float*)d_out;

    prep1<<<BB * NN, HH, 0, stream>>>(node, Wn, base_node, zg);
    prep2<<<BB + FE, HH, 0, stream>>>(graph, Wg, Wmg, Wee, Wme, mg, We);
    prep3<<<BB * NN, HH, 0, stream>>>(edge, adj, eg16, jl, cnt);

    for (int t = 0; t < TT; ++t) {
        for (int ms = 0; ms < 3; ++ms) {
            k1_gemm<<<512, 256, 0, stream>>>(zg, Wm1, Wm2, Wo1, mg,
                                             m1p, m2, o1);
            k2_max<<<BB * NN, HH, 0, stream>>>(eg16, jl, cnt, We, m1p, m2, o1,
                                               Wo2, Wdn, Wde, base_node, hints,
                                               Wh, zg, out, t, ms == 2 ? 1 : 0);
        }
    }
}

// Round 10
// 2057.715 us; speedup vs baseline: 1.4439x; 1.0890x over previous
//
#include <hip/hip_runtime.h>
#include <hip/hip_bf16.h>
#include <stdint.h>

#define BB 32
#define NN 128
#define TT 16
#define FN 16
#define FE 8
#define FG 8
#define FH 16
#define HH 128
#define DEC 64

// ws layout (floats):
// base_node @0        [524288]
// We        @524288   [1024]
// mg        @525312   [4096]
// m1p       @529408   [524288]
// m2        @1053696  [524288]
// o1        @1577984  [524288]
// hid       @2102272  [524288]
// eg16      @2626560  [2097152]
// jl (int)  @4723712  [524288]
// cnt (int) @5248000  [4096]
// zpart     @5252096  [25165824]  ([16 steps][3 mats][4096 rows][128])
// end 30417920 floats = 121.7 MB (ws = 256 MB)

__global__ __launch_bounds__(HH) void prep1(const float* __restrict__ node,
                                            const float* __restrict__ Wn,
                                            float* __restrict__ base_node,
                                            float* __restrict__ hid) {
    int row = blockIdx.x;
    int h = threadIdx.x;
    float acc = 0.f;
#pragma unroll
    for (int f = 0; f < FN; ++f)
        acc += node[row * FN + f] * Wn[f * HH + h];
    base_node[row * HH + h] = acc;
    hid[row * HH + h] = 0.f;
}

// grid = BB + FE blocks: 0..31 compute mg[b][h]; 32..39 compute We[f][h].
__global__ __launch_bounds__(HH) void prep2(const float* __restrict__ graph,
                                            const float* __restrict__ Wg,
                                            const float* __restrict__ Wmg,
                                            const float* __restrict__ Wee,
                                            const float* __restrict__ Wme,
                                            float* __restrict__ mg,
                                            float* __restrict__ We) {
    int h = threadIdx.x;
    if (blockIdx.x < BB) {
        int b = blockIdx.x;
        __shared__ float gf[HH];
        float acc = 0.f;
#pragma unroll
        for (int f = 0; f < FG; ++f) acc += graph[b * FG + f] * Wg[f * HH + h];
        gf[h] = acc;
        __syncthreads();
        float a2 = 0.f;
#pragma unroll 16
        for (int k = 0; k < HH; ++k) a2 += gf[k] * Wmg[k * HH + h];
        mg[b * HH + h] = a2;
    } else {
        int f = blockIdx.x - BB;
        float acc = 0.f;
#pragma unroll 16
        for (int k = 0; k < HH; ++k) acc += Wee[f * HH + k] * Wme[k * HH + h];
        We[f * HH + h] = acc;
    }
}

__device__ __forceinline__ uint32_t bf16rne(float v) {
    uint32_t b = __float_as_uint(v);
    return (b + 0x7fffu + ((b >> 16) & 1u)) >> 16;
}

// Compact valid senders into bf16-packed rows; pad count to multiple of 8
// with duplicates of the first valid entry (max is idempotent).
__global__ __launch_bounds__(HH) void prep3(const float* __restrict__ edge,
                                            const int* __restrict__ adj,
                                            uint4* __restrict__ eg16,
                                            int* __restrict__ jl,
                                            int* __restrict__ cnt) {
    int bi = blockIdx.x;
    int j = threadIdx.x;
    __shared__ int w0cnt, totc, j0s;
    bool valid = adj[(size_t)bi * NN + j] > 0;
    unsigned long long mask = __ballot(valid);
    int lane = j & 63;
    int wave = j >> 6;
    int prefix = __popcll(mask & ((1ull << lane) - 1ull));
    int wcount = __popcll(mask);
    if (wave == 0 && lane == 0) w0cnt = wcount;
    __syncthreads();
    int base = (wave == 1) ? w0cnt : 0;
    if (wave == 1 && lane == 0) totc = w0cnt + wcount;
    int pos = base + prefix;
    if (valid && pos == 0) j0s = j;
    __syncthreads();
    int c = totc;
    int cpad = (c + 7) & ~7;
    if (j == 0) cnt[bi] = cpad;

    if (valid) {
        jl[bi * NN + pos] = j;
        const float* src = edge + ((size_t)bi * NN + j) * FE;
        uint4 r;
        r.x = bf16rne(src[0]) | (bf16rne(src[1]) << 16);
        r.y = bf16rne(src[2]) | (bf16rne(src[3]) << 16);
        r.z = bf16rne(src[4]) | (bf16rne(src[5]) << 16);
        r.w = bf16rne(src[6]) | (bf16rne(src[7]) << 16);
        eg16[(size_t)bi * NN + pos] = r;
    }
    if (c > 0 && j >= c && j < cpad) {
        int j0 = j0s;
        jl[bi * NN + j] = j0;
        const float* src = edge + ((size_t)bi * NN + j0) * FE;
        uint4 r;
        r.x = bf16rne(src[0]) | (bf16rne(src[1]) << 16);
        r.y = bf16rne(src[2]) | (bf16rne(src[3]) << 16);
        r.z = bf16rne(src[4]) | (bf16rne(src[5]) << 16);
        r.w = bf16rne(src[6]) | (bf16rne(src[7]) << 16);
        eg16[(size_t)bi * NN + j] = r;
    }
}

// K0: nf-part GEMM for ALL 16 steps at once. 8192 blocks x 256 thr.
// Block = (step t, 8-row tile): zpart[t][m] = nf_t @ W_m[:128] (+mg for m=0).
__global__ __launch_bounds__(256) void k0_nf(
    const float* __restrict__ base_node, const float* __restrict__ hints,
    const float* __restrict__ Wh,
    const float* __restrict__ Wm1, const float* __restrict__ Wm2,
    const float* __restrict__ Wo1, const float* __restrict__ mg,
    float* __restrict__ zpart) {
    __shared__ float zs[8][HH];
    const int lane = threadIdx.x & 127;
    const int half = threadIdx.x >> 7;
    const int bid = blockIdx.x;
    const int t = bid >> 9;                       // 0..15
    const int bl = bid & 511;
    const int tile = (bl & 7) * 64 + (bl >> 3);   // XCD swizzle
    const int row0 = tile * 8;

#pragma unroll
    for (int r = 0; r < 4; ++r) {
        int rr = half * 4 + r;
        int row = row0 + rr;
        float nf = base_node[row * HH + lane];
        if (t > 0) {
            const float* hr = hints + ((size_t)(t - 1) * BB * NN + row) * FH;
#pragma unroll
            for (int f = 0; f < FH; ++f) nf = fmaf(hr[f], Wh[f * HH + lane], nf);
        }
        zs[rr][lane] = nf;
    }
    __syncthreads();

    float acc[4][3];
#pragma unroll
    for (int r = 0; r < 4; ++r) { acc[r][0] = 0.f; acc[r][1] = 0.f; acc[r][2] = 0.f; }
    const int h4 = half * 4;

#pragma unroll 4
    for (int kk = 0; kk < 32; ++kk) {
        const int k0 = kk * 4;
        float4 z0 = *(const float4*)&zs[h4 + 0][k0];
        float4 z1 = *(const float4*)&zs[h4 + 1][k0];
        float4 z2 = *(const float4*)&zs[h4 + 2][k0];
        float4 z3 = *(const float4*)&zs[h4 + 3][k0];
#define K0U(COMP, KO)                                                   \
        {                                                               \
            const float w1 = Wm1[(k0 + KO) * HH + lane];                \
            const float w2 = Wm2[(k0 + KO) * HH + lane];                \
            const float w3 = Wo1[(k0 + KO) * HH + lane];                \
            acc[0][0] = fmaf(z0.COMP, w1, acc[0][0]);                   \
            acc[1][0] = fmaf(z1.COMP, w1, acc[1][0]);                   \
            acc[2][0] = fmaf(z2.COMP, w1, acc[2][0]);                   \
            acc[3][0] = fmaf(z3.COMP, w1, acc[3][0]);                   \
            acc[0][1] = fmaf(z0.COMP, w2, acc[0][1]);                   \
            acc[1][1] = fmaf(z1.COMP, w2, acc[1][1]);                   \
            acc[2][1] = fmaf(z2.COMP, w2, acc[2][1]);                   \
            acc[3][1] = fmaf(z3.COMP, w2, acc[3][1]);                   \
            acc[0][2] = fmaf(z0.COMP, w3, acc[0][2]);                   \
            acc[1][2] = fmaf(z1.COMP, w3, acc[1][2]);                   \
            acc[2][2] = fmaf(z2.COMP, w3, acc[2][2]);                   \
            acc[3][2] = fmaf(z3.COMP, w3, acc[3][2]);                   \
        }
        K0U(x, 0) K0U(y, 1) K0U(z, 2) K0U(w, 3)
#undef K0U
    }

    const int b = row0 >> 7;
    const float mgv = mg[b * HH + lane];
#pragma unroll
    for (int r = 0; r < 4; ++r) {
        const int row = row0 + h4 + r;
        const size_t o = ((size_t)t * 3 * 4096) * HH;
        zpart[o + ((size_t)0 * 4096 + row) * HH + lane] = acc[r][0] + mgv;
        zpart[o + ((size_t)1 * 4096 + row) * HH + lane] = acc[r][1];
        zpart[o + ((size_t)2 * 4096 + row) * HH + lane] = acc[r][2];
    }
}

// K1H: hidden-part GEMM (K=128) + zpart add. 512 blocks x 256 thr, 8 rows/block.
__global__ __launch_bounds__(256) void k1_gemm(
    const float* __restrict__ hid,
    const float* __restrict__ Wm1, const float* __restrict__ Wm2,
    const float* __restrict__ Wo1, const float* __restrict__ zpart,
    float* __restrict__ m1p, float* __restrict__ m2, float* __restrict__ o1,
    int t) {
    __shared__ float zs[8][HH];
    const int lane = threadIdx.x & 127;
    const int half = threadIdx.x >> 7;
    const int bid = blockIdx.x;
    const int tile = (bid & 7) * 64 + (bid >> 3);
    const int row0 = tile * 8;

#pragma unroll
    for (int r = 0; r < 4; ++r) {
        int rr = half * 4 + r;
        zs[rr][lane] = hid[(row0 + rr) * HH + lane];
    }
    __syncthreads();

    float acc[4][3];
#pragma unroll
    for (int r = 0; r < 4; ++r) { acc[r][0] = 0.f; acc[r][1] = 0.f; acc[r][2] = 0.f; }
    const int h4 = half * 4;
    const float* __restrict__ W1 = Wm1 + HH * HH;   // rows 128..255
    const float* __restrict__ W2 = Wm2 + HH * HH;
    const float* __restrict__ W3 = Wo1 + HH * HH;

#pragma unroll 4
    for (int kk = 0; kk < 32; ++kk) {
        const int k0 = kk * 4;
        float4 z0 = *(const float4*)&zs[h4 + 0][k0];
        float4 z1 = *(const float4*)&zs[h4 + 1][k0];
        float4 z2 = *(const float4*)&zs[h4 + 2][k0];
        float4 z3 = *(const float4*)&zs[h4 + 3][k0];
#define K1U(COMP, KO)                                                   \
        {                                                               \
            const float w1 = W1[(k0 + KO) * HH + lane];                 \
            const float w2 = W2[(k0 + KO) * HH + lane];                 \
            const float w3 = W3[(k0 + KO) * HH + lane];                 \
            acc[0][0] = fmaf(z0.COMP, w1, acc[0][0]);                   \
            acc[1][0] = fmaf(z1.COMP, w1, acc[1][0]);                   \
            acc[2][0] = fmaf(z2.COMP, w1, acc[2][0]);                   \
            acc[3][0] = fmaf(z3.COMP, w1, acc[3][0]);                   \
            acc[0][1] = fmaf(z0.COMP, w2, acc[0][1]);                   \
            acc[1][1] = fmaf(z1.COMP, w2, acc[1][1]);                   \
            acc[2][1] = fmaf(z2.COMP, w2, acc[2][1]);                   \
            acc[3][1] = fmaf(z3.COMP, w2, acc[3][1]);                   \
            acc[0][2] = fmaf(z0.COMP, w3, acc[0][2]);                   \
            acc[1][2] = fmaf(z1.COMP, w3, acc[1][2]);                   \
            acc[2][2] = fmaf(z2.COMP, w3, acc[2][2]);                   \
            acc[3][2] = fmaf(z3.COMP, w3, acc[3][2]);                   \
        }
        K1U(x, 0) K1U(y, 1) K1U(z, 2) K1U(w, 3)
#undef K1U
    }

    const size_t zo = ((size_t)t * 3 * 4096) * HH;
#pragma unroll
    for (int r = 0; r < 4; ++r) {
        const int row = row0 + h4 + r;
        m1p[row * HH + lane] = acc[r][0] + zpart[zo + ((size_t)0 * 4096 + row) * HH + lane];
        m2[row * HH + lane]  = acc[r][1] + zpart[zo + ((size_t)1 * 4096 + row) * HH + lane];
        o1[row * HH + lane]  = acc[r][2] + zpart[zo + ((size_t)2 * 4096 + row) * HH + lane];
    }
}

// K2: 128 threads (h), serial compacted j-loop, unroll-8 batches, bf16 eg rows.
__global__ __launch_bounds__(HH) void k2_max(
    const uint4* __restrict__ eg16, const int* __restrict__ jl,
    const int* __restrict__ cnt, const float* __restrict__ We,
    const float* __restrict__ m1p, const float* __restrict__ m2,
    const float* __restrict__ o1, const float* __restrict__ Wo2,
    const float* __restrict__ Wdn, const float* __restrict__ Wde,
    float* __restrict__ hid, float* __restrict__ out, int t, int last) {
    __shared__ float agg_lds[HH];
    __shared__ float hnew_lds[HH];
    const int h = threadIdx.x;
    const int bid = blockIdx.x;
    const int bi = (bid & 7) * 512 + (bid >> 3);
    const int b = bi >> 7;

    const float we0 = We[0 * HH + h], we1 = We[1 * HH + h];
    const float we2 = We[2 * HH + h], we3 = We[3 * HH + h];
    const float we4 = We[4 * HH + h], we5 = We[5 * HH + h];
    const float we6 = We[6 * HH + h], we7 = We[7 * HH + h];

    const uint4* __restrict__ egp = eg16 + (size_t)bi * NN;
    const int* __restrict__ jlb = jl + bi * NN;
    const float* __restrict__ m2b = m2 + (size_t)b * NN * HH;
    const int cp = cnt[bi];
    const float m1v = m1p[bi * HH + h];
    const float o1v = o1[bi * HH + h];

    float M = -3e38f;
    const int nch = cp >> 3;
    for (int ch = 0; ch < nch; ++ch) {
        const int k0 = ch * 8;
        uint4 raw[8];
        int jj[8];
        float mv[8];
#pragma unroll
        for (int s = 0; s < 8; ++s) raw[s] = egp[k0 + s];
#pragma unroll
        for (int s = 0; s < 8; ++s) jj[s] = jlb[k0 + s];
#pragma unroll
        for (int s = 0; s < 8; ++s) mv[s] = m2b[jj[s] * HH + h];
#pragma unroll
        for (int s = 0; s < 8; ++s) {
            uint32_t x = raw[s].x, y = raw[s].y, z = raw[s].z, w = raw[s].w;
            float e = __uint_as_float(x << 16) * we0;
            e = fmaf(__uint_as_float(x & 0xffff0000u), we1, e);
            e = fmaf(__uint_as_float(y << 16), we2, e);
            e = fmaf(__uint_as_float(y & 0xffff0000u), we3, e);
            e = fmaf(__uint_as_float(z << 16), we4, e);
            e = fmaf(__uint_as_float(z & 0xffff0000u), we5, e);
            e = fmaf(__uint_as_float(w << 16), we6, e);
            e = fmaf(__uint_as_float(w & 0xffff0000u), we7, e);
            M = fmaxf(M, e + mv[s]);
        }
    }
    float agg = (cp > 0) ? fmaxf(m1v + M, 0.f) : -1e9f;
    agg_lds[h] = agg;
    __syncthreads();

    float acc = o1v;
    const float4* a4 = (const float4*)agg_lds;
#pragma unroll 8
    for (int kk = 0; kk < 32; ++kk) {
        float4 a = a4[kk];
        acc = fmaf(a.x, Wo2[(kk * 4 + 0) * HH + h], acc);
        acc = fmaf(a.y, Wo2[(kk * 4 + 1) * HH + h], acc);
        acc = fmaf(a.z, Wo2[(kk * 4 + 2) * HH + h], acc);
        acc = fmaf(a.w, Wo2[(kk * 4 + 3) * HH + h], acc);
    }
    float hv = fmaxf(acc, 0.f);
    hid[bi * HH + h] = hv;

    if (last) {
        hnew_lds[h] = hv;
        __syncthreads();
        if (h < DEC) {
            float a = 0.f, e2 = 0.f;
            const float4* h4p = (const float4*)hnew_lds;
#pragma unroll 8
            for (int kk = 0; kk < 32; ++kk) {
                float4 hv4 = h4p[kk];
                float4 av4 = a4[kk];
                a = fmaf(hv4.x, Wdn[(kk * 4 + 0) * DEC + h], a);
                a = fmaf(hv4.y, Wdn[(kk * 4 + 1) * DEC + h], a);
                a = fmaf(hv4.z, Wdn[(kk * 4 + 2) * DEC + h], a);
                a = fmaf(hv4.w, Wdn[(kk * 4 + 3) * DEC + h], a);
                e2 = fmaf(av4.x, Wde[(kk * 4 + 0) * DEC + h], e2);
                e2 = fmaf(av4.y, Wde[(kk * 4 + 1) * DEC + h], e2);
                e2 = fmaf(av4.z, Wde[(kk * 4 + 2) * DEC + h], e2);
                e2 = fmaf(av4.w, Wde[(kk * 4 + 3) * DEC + h], e2);
            }
            out[(((size_t)t * BB + b) * NN + (bi & 127)) * DEC + h] = a + e2;
        }
    }
}

extern "C" void kernel_launch(void* const* d_in, const int* in_sizes, int n_in,
                              void* d_out, int out_size, void* d_ws, size_t ws_size,
                              hipStream_t stream) {
    const float* node = (const float*)d_in[0];
    const float* edge = (const float*)d_in[1];
    const float* graph = (const float*)d_in[2];
    const float* hints = (const float*)d_in[3];
    const int* adj = (const int*)d_in[4];
    const float* Wn = (const float*)d_in[5];
    const float* Wh = (const float*)d_in[6];
    const float* Wee = (const float*)d_in[7];
    const float* Wg = (const float*)d_in[8];
    const float* Wm1 = (const float*)d_in[9];
    const float* Wm2 = (const float*)d_in[10];
    const float* Wme = (const float*)d_in[11];
    const float* Wmg = (const float*)d_in[12];
    const float* Wo1 = (const float*)d_in[13];
    const float* Wo2 = (const float*)d_in[14];
    const float* Wdn = (const float*)d_in[15];
    const float* Wde = (const float*)d_in[16];

    float* ws = (float*)d_ws;
    float* base_node = ws;
    float* We = ws + 524288;
    float* mg = ws + 525312;
    float* m1p = ws + 529408;
    float* m2 = ws + 1053696;
    float* o1 = ws + 1577984;
    float* hid = ws + 2102272;
    uint4* eg16 = (uint4*)(ws + 2626560);
    int* jl = (int*)(ws + 4723712);
    int* cnt = (int*)(ws + 5248000);
    float* zpart = ws + 5252096;
    float* out = (float*)d_out;

    prep1<<<BB * NN, HH, 0, stream>>>(node, Wn, base_node, hid);
    prep2<<<BB + FE, HH, 0, stream>>>(graph, Wg, Wmg, Wee, Wme, mg, We);
    prep3<<<BB * NN, HH, 0, stream>>>(edge, adj, eg16, jl, cnt);
    k0_nf<<<8192, 256, 0, stream>>>(base_node, hints, Wh, Wm1, Wm2, Wo1, mg,
                                    zpart);

    for (int t = 0; t < TT; ++t) {
        for (int ms = 0; ms < 3; ++ms) {
            k1_gemm<<<512, 256, 0, stream>>>(hid, Wm1, Wm2, Wo1, zpart,
                                             m1p, m2, o1, t);
            k2_max<<<BB * NN, HH, 0, stream>>>(eg16, jl, cnt, We, m1p, m2, o1,
                                               Wo2, Wdn, Wde, hid, out, t,
                                               ms == 2 ? 1 : 0);
        }
    }
}